// Round 16
// baseline (87.125 us; speedup 1.0000x reference)
//
#include <hip/hip_runtime.h>
#include <stdint.h>

#define HW  3136
#define HWP 3200
#define NB  8

typedef unsigned short ushort_t;
typedef __attribute__((ext_vector_type(8))) _Float16 f16x8;
typedef __attribute__((ext_vector_type(8))) unsigned short ushort8;
typedef __attribute__((ext_vector_type(4))) float f32x4;

__device__ __forceinline__ void gload16(const void* g, void* l) {
  __builtin_amdgcn_global_load_lds(
      (const __attribute__((address_space(1))) void*)g,
      (__attribute__((address_space(3))) void*)l, 16, 0, 0);
}

// ---------------- Kernel 1: L2-normalize over C=64, cast fp32 -> fp16,
// store (n,p,c) rows (128B) with 16B-chunk XOR swizzle (chunk ^= p&7) into
// HWP=3200-row padded arrays. XCD-pinned (n = blockIdx.x & 7, grid 400=8*50).
// pb==49 writes zero pad rows + sentinel centers.
__global__ __launch_bounds__(256) void norm_cast_kernel(
    const float* __restrict__ q, const float* __restrict__ k,
    const float* __restrict__ cqx, const float* __restrict__ cqy,
    const float* __restrict__ ckx, const float* __restrict__ cky,
    ushort_t* __restrict__ qh, ushort_t* __restrict__ kh,
    float* __restrict__ cqxp, float* __restrict__ cqyp,
    float* __restrict__ ckxp, float* __restrict__ ckyp) {
  const int isK = blockIdx.y;
  const float* src = isK ? k : q;
  ushort_t* dh = isK ? kh : qh;
  float* cxp = isK ? ckxp : cqxp;
  float* cyp = isK ? ckyp : cqyp;
  const float* cx = isK ? ckx : cqx;
  const float* cy = isK ? cky : cqy;
  const float sent = isK ? -1e9f : 1e9f;
  const int n = blockIdx.x & 7, pb = blockIdx.x >> 3;
  const int tid = threadIdx.x;

  if (pb == 49) {  // padding rows 3136..3199
    uint4 z = make_uint4(0u, 0u, 0u, 0u);
    uint4* dst = (uint4*)(dh + ((size_t)n * HWP + HW) * 64);
    #pragma unroll
    for (int u = tid; u < 512; u += 256) dst[u] = z;
    if (tid < 64) {
      cxp[(size_t)n * HWP + HW + tid] = sent;
      cyp[(size_t)n * HWP + HW + tid] = sent;
    }
    return;
  }

  const int p0 = pb * 64;
  __shared__ float tile[64][65];
  __shared__ float psum[4][64];
  __shared__ float invs[64];
  const int px = tid & 63, grp = tid >> 6;

  for (int c = grp; c < 64; c += 4)
    tile[c][px] = src[(size_t)(n * 64 + c) * HW + p0 + px];
  if (tid < 64) {
    cxp[(size_t)n * HWP + p0 + tid] = cx[(size_t)n * HW + p0 + tid];
    cyp[(size_t)n * HWP + p0 + tid] = cy[(size_t)n * HW + p0 + tid];
  }
  __syncthreads();

  float s = 0.f;
  #pragma unroll
  for (int e = 0; e < 16; ++e) { float v = tile[grp * 16 + e][px]; s += v * v; }
  psum[grp][px] = s;
  __syncthreads();
  if (tid < 64) {
    float t = psum[0][tid] + psum[1][tid] + psum[2][tid] + psum[3][tid];
    invs[tid] = 1.0f / fmaxf(sqrtf(t), 1e-8f);
  }
  __syncthreads();

  #pragma unroll
  for (int s2 = 0; s2 < 2; ++s2) {
    const int slot = s2 * 256 + tid;   // 0..511
    const int pl = slot >> 3, ch = slot & 7;
    const float iv = invs[pl];
    ushort8 w;
    #pragma unroll
    for (int e = 0; e < 8; ++e) {
      float v = tile[ch * 8 + e][pl] * iv;
      _Float16 h = (_Float16)v;
      w[e] = __builtin_bit_cast(ushort_t, h);
    }
    const int p = p0 + pl;
    *(ushort8*)(dh + ((size_t)n * HWP + p) * 64 + (ch ^ (p & 7)) * 8) = w;
  }
}

// ---------------- Kernel 2: masked pair-sum GEMM — 4 wave-private pipelines
// per block, zero main-loop barriers, T15 double-pipeline: per body,
// stage(t+2) -> vmcnt(5) -> ds_read(t+1) -> EPILOGUE(t) [VALU, overlaps ds
// latency] -> MFMA(t+1) [latency drains under next body]. Two acc/center
// sets (A=even chunks, B=odd), all indices compile-time (no scratch).
// Grid 1000 = 8 batches (bid&7 -> XCD) x 125; wave w: i_tile = windex/10,
// j_split = windex%10 (320 k-rows = 10 chunks of 32, dbuf in wave's own
// 8.7KB LDS slice). launch_bounds (256,2): (256,4) caused 64-VGPR spill (R12).
__global__ __launch_bounds__(256, 2) void pair_sum_kernel(
    const ushort_t* __restrict__ qh, const ushort_t* __restrict__ kh,
    const float* __restrict__ cqxp, const float* __restrict__ cqyp,
    const float* __restrict__ ckxp, const float* __restrict__ ckyp,
    float* __restrict__ partial) {
  __shared__ __align__(16) char smem[4 * 8704];   // per-wave 2 x (4096 K + 256 ctr)
  __shared__ float redns[8];
  const int bid = blockIdx.x;
  const int n = bid & 7;             // XCD = bid % 8 -> one batch per XCD
  const int rem = bid >> 3;          // 0..124
  const int tid = threadIdx.x, lane = tid & 63, wid = tid >> 6;
  const int windex = rem * 4 + wid;  // 0..499
  const int i0 = (windex / 10) * 64; // 50 q-tiles
  const int js = windex % 10;        // j-range start = js*320
  const int lrow = lane & 15, lhi = lane >> 4;
  const size_t base = (size_t)n * HWP * 64;
  const size_t cbase = (size_t)n * HWP;
  char* ws = smem + wid * 8704;      // this wave's private LDS slice

  // A-fragments straight from swizzled global (same XOR formula as LDS read)
  f16x8 Ah[2][4];
  #pragma unroll
  for (int kk = 0; kk < 2; ++kk)
    #pragma unroll
    for (int t = 0; t < 4; ++t) {
      const int row = i0 + t * 16 + lrow;
      Ah[kk][t] = *(const f16x8*)(qh + base + (size_t)row * 64 +
                                  (size_t)(((kk * 4 + lhi) ^ (row & 7)) * 8));
    }

  // q-centers in regs as f32x4 (C/D row = lhi*4 + r)
  f32x4 qcx4[4], qcy4[4];
  #pragma unroll
  for (int tr = 0; tr < 4; ++tr) {
    qcx4[tr] = *(const f32x4*)(cqxp + cbase + i0 + tr * 16 + lhi * 4);
    qcy4[tr] = *(const f32x4*)(cqyp + cbase + i0 + tr * 16 + lhi * 4);
  }

  // Each STAGE = exactly 5 VMEM ops (4 tile gloads + 1 center gload)
  #define STAGE(c, b)                                                          \
  {                                                                            \
    const int j0 = js * 320 + (c) * 32;                                        \
    _Pragma("unroll")                                                          \
    for (int pass = 0; pass < 4; ++pass) {                                     \
      const int idx = pass * 64 + lane;                                        \
      gload16(kh + base + (size_t)(j0 + (idx >> 3)) * 64 + (idx & 7) * 8,      \
              ws + (b) * 4352 + idx * 16);                                     \
    }                                                                          \
    if (lane < 16) {                                                           \
      const float* csrc = (lane < 8) ? (ckxp + cbase + j0 + lane * 4)          \
                                     : (ckyp + cbase + j0 + (lane - 8) * 4);   \
      gload16(csrc, ws + (b) * 4352 + 4096 + lane * 16);                       \
    }                                                                          \
  }

  #define LOADB(B)                                                             \
  {                                                                            \
    _Pragma("unroll")                                                          \
    for (int kk = 0; kk < 2; ++kk)                                             \
      _Pragma("unroll")                                                        \
      for (int t2 = 0; t2 < 2; ++t2) {                                         \
        const int jr = t2 * 16 + lrow;                                         \
        const int boff = jr * 128 + (((kk * 4 + lhi) ^ (jr & 7)) << 4);        \
        Bh[kk][t2] = *(const f16x8*)(ws + (B) * 4352 + boff);                  \
      }                                                                        \
  }

  #define LOADC(B, KX, KY)                                                     \
  {                                                                            \
    const float* skc = (const float*)(ws + (B) * 4352 + 4096);                 \
    KX[0] = skc[lrow];      KX[1] = skc[16 + lrow];                            \
    KY[0] = skc[32 + lrow]; KY[1] = skc[48 + lrow];                            \
  }

  #define ZERO(ACC)                                                            \
    _Pragma("unroll")                                                          \
    for (int a = 0; a < 4; ++a)                                                \
      _Pragma("unroll")                                                        \
      for (int c2 = 0; c2 < 2; ++c2) ACC[a][c2] = (f32x4){0.f, 0.f, 0.f, 0.f};

  #define DOMFMA(ACC)                                                          \
    __builtin_amdgcn_s_setprio(1);                                             \
    _Pragma("unroll")                                                          \
    for (int kk = 0; kk < 2; ++kk)                                             \
      _Pragma("unroll")                                                        \
      for (int tr = 0; tr < 4; ++tr)                                           \
        _Pragma("unroll")                                                      \
        for (int tc = 0; tc < 2; ++tc)                                         \
          ACC[tr][tc] = __builtin_amdgcn_mfma_f32_16x16x32_f16(                \
              Ah[kk][tr], Bh[kk][tc], ACC[tr][tc], 0, 0, 0);                   \
    __builtin_amdgcn_s_setprio(0);

  // vectorized f32x4 epilogue (compiler emits v_pk_* where possible)
  #define EPILOGUE(ACC, KX, KY)                                                \
  {                                                                            \
    _Pragma("unroll")                                                          \
    for (int tr = 0; tr < 4; ++tr) {                                           \
      _Pragma("unroll")                                                        \
      for (int tc = 0; tc < 2; ++tc) {                                         \
        f32x4 kxb = (f32x4){KX[tc], KX[tc], KX[tc], KX[tc]};                   \
        f32x4 kyb = (f32x4){KY[tc], KY[tc], KY[tc], KY[tc]};                   \
        f32x4 dx = qcx4[tr] - kxb;                                             \
        f32x4 dy = qcy4[tr] - kyb;                                             \
        f32x4 d2 = dx * dx + dy * dy;                                          \
        f32x4 sel;                                                             \
        _Pragma("unroll")                                                      \
        for (int r = 0; r < 4; ++r) {                                          \
          const bool m = d2[r] < 0.48999998f;  /* 0.7^2 */                     \
          sel[r] = m ? ACC[tr][tc][r] : 0.f;                                   \
          dcnt += (unsigned int)__popcll(__ballot(m));  /* SALU count */       \
        }                                                                      \
        num4 += sel;                                                           \
      }                                                                        \
    }                                                                          \
  }

  // BODY(I): stage(I+2) -> vmcnt -> ds_read(I+1) -> epilogue(I) -> MFMA(I+1)
  #define BODY(I, ACUR, ANXT, KXC, KYC, KXN, KYN)                              \
  {                                                                            \
    if ((I) + 2 < 10) STAGE((I) + 2, (I) & 1);                                 \
    if ((I) + 1 < 10) {                                                        \
      if ((I) + 2 < 10) {                                                      \
        asm volatile("s_waitcnt vmcnt(5)" ::: "memory");                       \
      } else {                                                                 \
        asm volatile("s_waitcnt vmcnt(0)" ::: "memory");                       \
      }                                                                        \
      LOADB(((I) + 1) & 1);                                                    \
      LOADC(((I) + 1) & 1, KXN, KYN);                                          \
      ZERO(ANXT);                                                              \
    }                                                                          \
    EPILOGUE(ACUR, KXC, KYC);                                                  \
    if ((I) + 1 < 10) { DOMFMA(ANXT); }                                        \
  }

  f32x4 num4 = (f32x4){0.f, 0.f, 0.f, 0.f};
  unsigned int dcnt = 0;
  f32x4 accA[4][2], accB[4][2];
  float kxA[2], kyA[2], kxB[2], kyB[2];
  f16x8 Bh[2][2];

  // prologue: stage chunks 0,1; compute chunk 0 into accA
  STAGE(0, 0);
  STAGE(1, 1);
  asm volatile("s_waitcnt vmcnt(5)" ::: "memory");   // chunk 0 resident
  LOADB(0);
  LOADC(0, kxA, kyA);
  ZERO(accA);
  DOMFMA(accA);

  BODY(0, accA, accB, kxA, kyA, kxB, kyB);
  BODY(1, accB, accA, kxB, kyB, kxA, kyA);
  BODY(2, accA, accB, kxA, kyA, kxB, kyB);
  BODY(3, accB, accA, kxB, kyB, kxA, kyA);
  BODY(4, accA, accB, kxA, kyA, kxB, kyB);
  BODY(5, accB, accA, kxB, kyB, kxA, kyA);
  BODY(6, accA, accB, kxA, kyA, kxB, kyB);
  BODY(7, accB, accA, kxB, kyB, kxA, kyA);
  BODY(8, accA, accB, kxA, kyA, kxB, kyB);
  BODY(9, accB, accA, kxB, kyB, kxA, kyA);   // epilogue-only (I+1 == 10)

  #undef BODY
  #undef EPILOGUE
  #undef DOMFMA
  #undef ZERO
  #undef LOADC
  #undef LOADB
  #undef STAGE

  // wave-level reduce, then 4-way merge (first and only barrier)
  float num = (num4[0] + num4[1]) + (num4[2] + num4[3]);
  #pragma unroll
  for (int off = 32; off > 0; off >>= 1) num += __shfl_down(num, off);
  if (lane == 0) {
    redns[wid * 2] = num;
    redns[wid * 2 + 1] = (float)dcnt;
  }
  __syncthreads();
  if (tid == 0) {
    float tn = 0.f, td = 0.f;
    #pragma unroll
    for (int w = 0; w < 4; ++w) { tn += redns[w * 2]; td += redns[w * 2 + 1]; }
    partial[bid * 2] = tn;
    partial[bid * 2 + 1] = td;
  }
}

// ---------------- Kernel 3: final reduce over 125 partials per batch.
// partial[] indexed by bid: batch n owns bids {n, n+8, ...}.
__global__ __launch_bounds__(256) void finalize_kernel(const float* __restrict__ partial,
                                                       float* __restrict__ out) {
  __shared__ float rat[8];
  const int tid = threadIdx.x;
  const int n = tid >> 5, s = tid & 31;
  float num = 0.f, den = 0.f;
  for (int p = s; p < 125; p += 32) {
    num += partial[(p * 8 + n) * 2];
    den += partial[(p * 8 + n) * 2 + 1];
  }
  #pragma unroll
  for (int off = 16; off > 0; off >>= 1) {
    num += __shfl_down(num, off, 32);
    den += __shfl_down(den, off, 32);
  }
  if (s == 0) rat[n] = num / (den + 1e-6f);
  __syncthreads();
  if (tid == 0) {
    float t = 0.f;
    #pragma unroll
    for (int i = 0; i < 8; ++i) t += rat[i];
    out[0] = -0.25f * t;  // -2 * mean over 8 batches
  }
}

extern "C" void kernel_launch(void* const* d_in, const int* in_sizes, int n_in,
                              void* d_out, int out_size, void* d_ws, size_t ws_size,
                              hipStream_t stream) {
  const float* q   = (const float*)d_in[0];
  const float* k   = (const float*)d_in[1];
  const float* cqx = (const float*)d_in[2];
  const float* cqy = (const float*)d_in[3];
  const float* ckx = (const float*)d_in[4];
  const float* cky = (const float*)d_in[5];

  const size_t ARR = (size_t)NB * HWP * 64;
  ushort_t* qh = (ushort_t*)d_ws;
  ushort_t* kh = qh + ARR;
  float* cqxp = (float*)(kh + ARR);
  float* cqyp = cqxp + (size_t)NB * HWP;
  float* ckxp = cqyp + (size_t)NB * HWP;
  float* ckyp = ckxp + (size_t)NB * HWP;
  float* partial = ckyp + (size_t)NB * HWP;

  norm_cast_kernel<<<dim3(400, 2), 256, 0, stream>>>(
      q, k, cqx, cqy, ckx, cky, qh, kh, cqxp, cqyp, ckxp, ckyp);
  pair_sum_kernel<<<1000, 256, 0, stream>>>(
      qh, kh, cqxp, cqyp, ckxp, ckyp, partial);
  finalize_kernel<<<1, 256, 0, stream>>>(partial, (float*)d_out);
}

// Round 17
// 36.612 us; speedup vs baseline: 2.3797x; 2.3797x over previous
//
#include <hip/hip_runtime.h>
#include <stdint.h>

#define HW  3136
#define HWP 3200
#define NB  8

typedef unsigned short ushort_t;
typedef __attribute__((ext_vector_type(8))) _Float16 f16x8;
typedef __attribute__((ext_vector_type(8))) unsigned short ushort8;
typedef __attribute__((ext_vector_type(4))) float f32x4;
typedef __attribute__((ext_vector_type(2))) float f32x2;

__device__ __forceinline__ void gload16(const void* g, void* l) {
  __builtin_amdgcn_global_load_lds(
      (const __attribute__((address_space(1))) void*)g,
      (__attribute__((address_space(3))) void*)l, 16, 0, 0);
}

// ---------------- Kernel 1: L2-normalize over C=64, cast fp32 -> fp16,
// store (n,p,c) rows (128B) with 16B-chunk XOR swizzle (chunk ^= p&7) into
// HWP=3200-row padded arrays. XCD-pinned (n = blockIdx.x & 7, grid 400=8*50).
// pb==49 writes zero pad rows + sentinel centers.
__global__ __launch_bounds__(256) void norm_cast_kernel(
    const float* __restrict__ q, const float* __restrict__ k,
    const float* __restrict__ cqx, const float* __restrict__ cqy,
    const float* __restrict__ ckx, const float* __restrict__ cky,
    ushort_t* __restrict__ qh, ushort_t* __restrict__ kh,
    float* __restrict__ cqxp, float* __restrict__ cqyp,
    float* __restrict__ ckxp, float* __restrict__ ckyp) {
  const int isK = blockIdx.y;
  const float* src = isK ? k : q;
  ushort_t* dh = isK ? kh : qh;
  float* cxp = isK ? ckxp : cqxp;
  float* cyp = isK ? ckyp : cqyp;
  const float* cx = isK ? ckx : cqx;
  const float* cy = isK ? cky : cqy;
  const float sent = isK ? -1e9f : 1e9f;
  const int n = blockIdx.x & 7, pb = blockIdx.x >> 3;
  const int tid = threadIdx.x;

  if (pb == 49) {  // padding rows 3136..3199
    uint4 z = make_uint4(0u, 0u, 0u, 0u);
    uint4* dst = (uint4*)(dh + ((size_t)n * HWP + HW) * 64);
    #pragma unroll
    for (int u = tid; u < 512; u += 256) dst[u] = z;
    if (tid < 64) {
      cxp[(size_t)n * HWP + HW + tid] = sent;
      cyp[(size_t)n * HWP + HW + tid] = sent;
    }
    return;
  }

  const int p0 = pb * 64;
  __shared__ float tile[64][65];
  __shared__ float psum[4][64];
  __shared__ float invs[64];
  const int px = tid & 63, grp = tid >> 6;

  for (int c = grp; c < 64; c += 4)
    tile[c][px] = src[(size_t)(n * 64 + c) * HW + p0 + px];
  if (tid < 64) {
    cxp[(size_t)n * HWP + p0 + tid] = cx[(size_t)n * HW + p0 + tid];
    cyp[(size_t)n * HWP + p0 + tid] = cy[(size_t)n * HW + p0 + tid];
  }
  __syncthreads();

  float s = 0.f;
  #pragma unroll
  for (int e = 0; e < 16; ++e) { float v = tile[grp * 16 + e][px]; s += v * v; }
  psum[grp][px] = s;
  __syncthreads();
  if (tid < 64) {
    float t = psum[0][tid] + psum[1][tid] + psum[2][tid] + psum[3][tid];
    invs[tid] = 1.0f / fmaxf(sqrtf(t), 1e-8f);
  }
  __syncthreads();

  #pragma unroll
  for (int s2 = 0; s2 < 2; ++s2) {
    const int slot = s2 * 256 + tid;   // 0..511
    const int pl = slot >> 3, ch = slot & 7;
    const float iv = invs[pl];
    ushort8 w;
    #pragma unroll
    for (int e = 0; e < 8; ++e) {
      float v = tile[ch * 8 + e][pl] * iv;
      _Float16 h = (_Float16)v;
      w[e] = __builtin_bit_cast(ushort_t, h);
    }
    const int p = p0 + pl;
    *(ushort8*)(dh + ((size_t)n * HWP + p) * 64 + (ch ^ (p & 7)) * 8) = w;
  }
}

// ---------------- Kernel 2: masked pair-sum GEMM — 4 independent waves per
// block, zero main-loop barriers, wave-private counted-vmcnt pipeline.
// Grid 1000 = 8 batches (bid&7 -> XCD) x 125. Wave w owns windex =
// (bid>>3)*4 + w: i_tile = windex/10 (A-frags + q-centers in regs), j_split =
// windex%10 (320 k-rows, 10 chunks of 32, double-buffered in the wave's own
// 8.7KB LDS slice). Per chunk: issue STAGE(c+1) -> s_waitcnt vmcnt(5)
// [= chunk c's 5 loads drained, c+1's in flight] -> ds_read -> setprio(1)
// MFMA setprio(0) -> packed-f32 epilogue. launch_bounds (256,2): 4-waves/EU
// cap caused 64-VGPR squeeze + scratch spill (R12: FETCH 187MB, 81us).
// NOTE (R15/R16 post-mortems): chunk-order rotation (runtime index) and T15
// double-accumulator both push live state into scratch (VGPR 128, WRITE
// 124-142MB) — this ~110-VGPR configuration is the spill-free optimum.
__global__ __launch_bounds__(256, 2) void pair_sum_kernel(
    const ushort_t* __restrict__ qh, const ushort_t* __restrict__ kh,
    const float* __restrict__ cqxp, const float* __restrict__ cqyp,
    const float* __restrict__ ckxp, const float* __restrict__ ckyp,
    float* __restrict__ partial) {
  __shared__ __align__(16) char smem[4 * 8704];   // per-wave 2 x (4096 K + 256 ctr)
  __shared__ float redns[8];
  const int bid = blockIdx.x;
  const int n = bid & 7;             // XCD = bid % 8 -> one batch per XCD
  const int rem = bid >> 3;          // 0..124
  const int tid = threadIdx.x, lane = tid & 63, wid = tid >> 6;
  const int windex = rem * 4 + wid;  // 0..499
  const int i0 = (windex / 10) * 64; // 50 q-tiles
  const int js = windex % 10;        // j-range start = js*320
  const int lrow = lane & 15, lhi = lane >> 4;
  const size_t base = (size_t)n * HWP * 64;
  const size_t cbase = (size_t)n * HWP;
  char* ws = smem + wid * 8704;      // this wave's private LDS slice

  // A-fragments straight from swizzled global (same XOR formula as LDS read)
  f16x8 Ah[2][4];
  #pragma unroll
  for (int kk = 0; kk < 2; ++kk)
    #pragma unroll
    for (int t = 0; t < 4; ++t) {
      const int row = i0 + t * 16 + lrow;
      Ah[kk][t] = *(const f16x8*)(qh + base + (size_t)row * 64 +
                                  (size_t)(((kk * 4 + lhi) ^ (row & 7)) * 8));
    }

  // q-centers in regs; C/D row = lhi*4 + r  -> vector f32x4 loads
  float qcx[4][4], qcy[4][4];
  #pragma unroll
  for (int tr = 0; tr < 4; ++tr) {
    f32x4 vx = *(const f32x4*)(cqxp + cbase + i0 + tr * 16 + lhi * 4);
    f32x4 vy = *(const f32x4*)(cqyp + cbase + i0 + tr * 16 + lhi * 4);
    #pragma unroll
    for (int r = 0; r < 4; ++r) { qcx[tr][r] = vx[r]; qcy[tr][r] = vy[r]; }
  }

  // Each STAGE = exactly 5 VMEM ops (4 tile gloads + 1 center gload)
  #define STAGE(c, b)                                                          \
  {                                                                            \
    const int j0 = js * 320 + (c) * 32;                                        \
    _Pragma("unroll")                                                          \
    for (int pass = 0; pass < 4; ++pass) {                                     \
      const int idx = pass * 64 + lane;                                        \
      gload16(kh + base + (size_t)(j0 + (idx >> 3)) * 64 + (idx & 7) * 8,      \
              ws + (b) * 4352 + idx * 16);                                     \
    }                                                                          \
    if (lane < 16) {                                                           \
      const float* csrc = (lane < 8) ? (ckxp + cbase + j0 + lane * 4)          \
                                     : (ckyp + cbase + j0 + (lane - 8) * 4);   \
      gload16(csrc, ws + (b) * 4352 + 4096 + lane * 16);                       \
    }                                                                          \
  }

  f32x2 num2 = (f32x2){0.f, 0.f};
  unsigned int dcnt = 0;

  STAGE(0, 0);   // prologue: chunk 0 into buf 0

  #define CHUNK_BODY(c, b, DO_STAGE)                                           \
  {                                                                            \
    if (DO_STAGE) {                                                            \
      STAGE((c) + 1, (b) ^ 1);                        /* prefetch next */      \
      asm volatile("s_waitcnt vmcnt(5)" ::: "memory"); /* chunk c landed */    \
    } else {                                                                   \
      asm volatile("s_waitcnt vmcnt(0)" ::: "memory");                         \
    }                                                                          \
    f16x8 Bh[2][2];                                                            \
    _Pragma("unroll")                                                          \
    for (int kk = 0; kk < 2; ++kk)                                             \
      _Pragma("unroll")                                                        \
      for (int t2 = 0; t2 < 2; ++t2) {                                         \
        const int jr = t2 * 16 + lrow;                                         \
        const int boff = jr * 128 + (((kk * 4 + lhi) ^ (jr & 7)) << 4);        \
        Bh[kk][t2] = *(const f16x8*)(ws + (b) * 4352 + boff);                  \
      }                                                                        \
    const float* skc = (const float*)(ws + (b) * 4352 + 4096);                 \
    f32x2 kx2, ky2;                                                            \
    kx2.x = skc[lrow];       kx2.y = skc[16 + lrow];                           \
    ky2.x = skc[32 + lrow];  ky2.y = skc[48 + lrow];                           \
    f32x4 acc[4][2];                                                           \
    _Pragma("unroll")                                                          \
    for (int a = 0; a < 4; ++a)                                                \
      _Pragma("unroll")                                                        \
      for (int c2 = 0; c2 < 2; ++c2) acc[a][c2] = (f32x4){0.f, 0.f, 0.f, 0.f};\
    __builtin_amdgcn_s_setprio(1);                                             \
    _Pragma("unroll")                                                          \
    for (int kk = 0; kk < 2; ++kk)                                             \
      _Pragma("unroll")                                                        \
      for (int tr = 0; tr < 4; ++tr)                                           \
        _Pragma("unroll")                                                      \
        for (int tc = 0; tc < 2; ++tc)                                         \
          acc[tr][tc] = __builtin_amdgcn_mfma_f32_16x16x32_f16(                \
              Ah[kk][tr], Bh[kk][tc], acc[tr][tc], 0, 0, 0);                   \
    __builtin_amdgcn_s_setprio(0);                                             \
    _Pragma("unroll")                                                          \
    for (int tr = 0; tr < 4; ++tr) {                                           \
      _Pragma("unroll")                                                        \
      for (int r = 0; r < 4; ++r) {                                            \
        const float qx = qcx[tr][r], qy = qcy[tr][r];                          \
        f32x2 dx, dy;                                                          \
        dx.x = qx - kx2.x; dx.y = qx - kx2.y;                                  \
        dy.x = qy - ky2.x; dy.y = qy - ky2.y;                                  \
        f32x2 d2 = dx * dx;                                                    \
        d2.x = fmaf(dy.x, dy.x, d2.x);                                         \
        d2.y = fmaf(dy.y, dy.y, d2.y);                                         \
        const bool m0 = d2.x < 0.48999998f;  /* 0.7^2 */                       \
        const bool m1 = d2.y < 0.48999998f;                                    \
        f32x2 sel;                                                             \
        sel.x = m0 ? acc[tr][0][r] : 0.f;                                      \
        sel.y = m1 ? acc[tr][1][r] : 0.f;                                      \
        num2 += sel;                                                           \
        dcnt += (unsigned int)__popcll(__ballot(m0));  /* scalar pipe */       \
        dcnt += (unsigned int)__popcll(__ballot(m1));                          \
      }                                                                        \
    }                                                                          \
  }

  for (int it = 0; it < 5; ++it) {
    const int c0 = it * 2;
    CHUNK_BODY(c0, 0, true);                 // chunk 2it   (buf0), stage 2it+1
    CHUNK_BODY(c0 + 1, 1, (c0 + 2 < 10));    // chunk 2it+1 (buf1), stage 2it+2
  }
  #undef CHUNK_BODY
  #undef STAGE

  // wave-level reduce, then 4-way merge (first and only barrier)
  float num = num2.x + num2.y;
  #pragma unroll
  for (int off = 32; off > 0; off >>= 1) num += __shfl_down(num, off);
  if (lane == 0) {
    redns[wid * 2] = num;
    redns[wid * 2 + 1] = (float)dcnt;
  }
  __syncthreads();
  if (tid == 0) {
    float tn = 0.f, td = 0.f;
    #pragma unroll
    for (int w = 0; w < 4; ++w) { tn += redns[w * 2]; td += redns[w * 2 + 1]; }
    partial[bid * 2] = tn;
    partial[bid * 2 + 1] = td;
  }
}

// ---------------- Kernel 3: final reduce over 125 partials per batch.
// partial[] indexed by bid: batch n owns bids {n, n+8, ...}.
__global__ __launch_bounds__(256) void finalize_kernel(const float* __restrict__ partial,
                                                       float* __restrict__ out) {
  __shared__ float rat[8];
  const int tid = threadIdx.x;
  const int n = tid >> 5, s = tid & 31;
  float num = 0.f, den = 0.f;
  for (int p = s; p < 125; p += 32) {
    num += partial[(p * 8 + n) * 2];
    den += partial[(p * 8 + n) * 2 + 1];
  }
  #pragma unroll
  for (int off = 16; off > 0; off >>= 1) {
    num += __shfl_down(num, off, 32);
    den += __shfl_down(den, off, 32);
  }
  if (s == 0) rat[n] = num / (den + 1e-6f);
  __syncthreads();
  if (tid == 0) {
    float t = 0.f;
    #pragma unroll
    for (int i = 0; i < 8; ++i) t += rat[i];
    out[0] = -0.25f * t;  // -2 * mean over 8 batches
  }
}

extern "C" void kernel_launch(void* const* d_in, const int* in_sizes, int n_in,
                              void* d_out, int out_size, void* d_ws, size_t ws_size,
                              hipStream_t stream) {
  const float* q   = (const float*)d_in[0];
  const float* k   = (const float*)d_in[1];
  const float* cqx = (const float*)d_in[2];
  const float* cqy = (const float*)d_in[3];
  const float* ckx = (const float*)d_in[4];
  const float* cky = (const float*)d_in[5];

  const size_t ARR = (size_t)NB * HWP * 64;
  ushort_t* qh = (ushort_t*)d_ws;
  ushort_t* kh = qh + ARR;
  float* cqxp = (float*)(kh + ARR);
  float* cqyp = cqxp + (size_t)NB * HWP;
  float* ckxp = cqyp + (size_t)NB * HWP;
  float* ckyp = ckxp + (size_t)NB * HWP;
  float* partial = ckyp + (size_t)NB * HWP;

  norm_cast_kernel<<<dim3(400, 2), 256, 0, stream>>>(
      q, k, cqx, cqy, ckx, cky, qh, kh, cqxp, cqyp, ckxp, ckyp);
  pair_sum_kernel<<<1000, 256, 0, stream>>>(
      qh, kh, cqxp, cqyp, ckxp, ckyp, partial);
  finalize_kernel<<<1, 256, 0, stream>>>(partial, (float*)d_out);
}

// Round 19
// 36.447 us; speedup vs baseline: 2.3905x; 1.0045x over previous
//
#include <hip/hip_runtime.h>
#include <stdint.h>

#define HW  3136
#define HWP 3200
#define NB  8

typedef unsigned short ushort_t;
typedef __attribute__((ext_vector_type(8))) _Float16 f16x8;
typedef __attribute__((ext_vector_type(8))) unsigned short ushort8;
typedef __attribute__((ext_vector_type(4))) float f32x4;
typedef __attribute__((ext_vector_type(2))) float f32x2;

__device__ __forceinline__ void gload16(const void* g, void* l) {
  __builtin_amdgcn_global_load_lds(
      (const __attribute__((address_space(1))) void*)g,
      (__attribute__((address_space(3))) void*)l, 16, 0, 0);
}

// ---------------- Kernel 1: L2-normalize over C=64, cast fp32 -> fp16,
// store (n,p,c) rows (128B) with 16B-chunk XOR swizzle (chunk ^= p&7) into
// HWP=3200-row padded arrays. XCD-pinned (n = blockIdx.x & 7, grid 400=8*50).
// pb==49 writes zero pad rows + sentinel centers.
__global__ __launch_bounds__(256) void norm_cast_kernel(
    const float* __restrict__ q, const float* __restrict__ k,
    const float* __restrict__ cqx, const float* __restrict__ cqy,
    const float* __restrict__ ckx, const float* __restrict__ cky,
    ushort_t* __restrict__ qh, ushort_t* __restrict__ kh,
    float* __restrict__ cqxp, float* __restrict__ cqyp,
    float* __restrict__ ckxp, float* __restrict__ ckyp) {
  const int isK = blockIdx.y;
  const float* src = isK ? k : q;
  ushort_t* dh = isK ? kh : qh;
  float* cxp = isK ? ckxp : cqxp;
  float* cyp = isK ? ckyp : cqyp;
  const float* cx = isK ? ckx : cqx;
  const float* cy = isK ? cky : cqy;
  const float sent = isK ? -1e9f : 1e9f;
  const int n = blockIdx.x & 7, pb = blockIdx.x >> 3;
  const int tid = threadIdx.x;

  if (pb == 49) {  // padding rows 3136..3199
    uint4 z = make_uint4(0u, 0u, 0u, 0u);
    uint4* dst = (uint4*)(dh + ((size_t)n * HWP + HW) * 64);
    #pragma unroll
    for (int u = tid; u < 512; u += 256) dst[u] = z;
    if (tid < 64) {
      cxp[(size_t)n * HWP + HW + tid] = sent;
      cyp[(size_t)n * HWP + HW + tid] = sent;
    }
    return;
  }

  const int p0 = pb * 64;
  __shared__ float tile[64][65];
  __shared__ float psum[4][64];
  __shared__ float invs[64];
  const int px = tid & 63, grp = tid >> 6;

  for (int c = grp; c < 64; c += 4)
    tile[c][px] = src[(size_t)(n * 64 + c) * HW + p0 + px];
  if (tid < 64) {
    cxp[(size_t)n * HWP + p0 + tid] = cx[(size_t)n * HW + p0 + tid];
    cyp[(size_t)n * HWP + p0 + tid] = cy[(size_t)n * HW + p0 + tid];
  }
  __syncthreads();

  float s = 0.f;
  #pragma unroll
  for (int e = 0; e < 16; ++e) { float v = tile[grp * 16 + e][px]; s += v * v; }
  psum[grp][px] = s;
  __syncthreads();
  if (tid < 64) {
    float t = psum[0][tid] + psum[1][tid] + psum[2][tid] + psum[3][tid];
    invs[tid] = 1.0f / fmaxf(sqrtf(t), 1e-8f);
  }
  __syncthreads();

  #pragma unroll
  for (int s2 = 0; s2 < 2; ++s2) {
    const int slot = s2 * 256 + tid;   // 0..511
    const int pl = slot >> 3, ch = slot & 7;
    const float iv = invs[pl];
    ushort8 w;
    #pragma unroll
    for (int e = 0; e < 8; ++e) {
      float v = tile[ch * 8 + e][pl] * iv;
      _Float16 h = (_Float16)v;
      w[e] = __builtin_bit_cast(ushort_t, h);
    }
    const int p = p0 + pl;
    *(ushort8*)(dh + ((size_t)n * HWP + p) * 64 + (ch ^ (p & 7)) * 8) = w;
  }
}

// ---------------- Kernel 2: masked pair-sum GEMM — 4 independent waves per
// block, zero main-loop barriers, wave-private counted-vmcnt pipeline.
// Grid 1000 = 8 batches (bid&7 -> XCD) x 125. Wave w owns windex =
// (bid>>3)*4 + w: i_tile = windex/10 (A-frags + q-centers in regs), j_split =
// windex%10 (320 k-rows, 10 chunks of 32, double-buffered in the wave's own
// 8.7KB LDS slice). Per chunk: issue STAGE(c+1) -> s_waitcnt vmcnt(5)
// [= chunk c's 5 loads drained, c+1's in flight] -> ds_read -> setprio(1)
// MFMA setprio(0) -> packed-f32 epilogue. launch_bounds (256,2): 4-waves/EU
// cap caused 64-VGPR squeeze + scratch spill (R12: FETCH 187MB, 81us).
// NOTE (R15/R16/R18 post-mortems): chunk-order rotation (runtime index),
// T15 double-accumulator (live-state overflow), and the 32x16 small-tile
// variant all failed (spill or wrong results). This ~110-VGPR configuration
// is the verified optimum: 36.52us (R14) / 36.61us (R17), absmax 0.0.
__global__ __launch_bounds__(256, 2) void pair_sum_kernel(
    const ushort_t* __restrict__ qh, const ushort_t* __restrict__ kh,
    const float* __restrict__ cqxp, const float* __restrict__ cqyp,
    const float* __restrict__ ckxp, const float* __restrict__ ckyp,
    float* __restrict__ partial) {
  __shared__ __align__(16) char smem[4 * 8704];   // per-wave 2 x (4096 K + 256 ctr)
  __shared__ float redns[8];
  const int bid = blockIdx.x;
  const int n = bid & 7;             // XCD = bid % 8 -> one batch per XCD
  const int rem = bid >> 3;          // 0..124
  const int tid = threadIdx.x, lane = tid & 63, wid = tid >> 6;
  const int windex = rem * 4 + wid;  // 0..499
  const int i0 = (windex / 10) * 64; // 50 q-tiles
  const int js = windex % 10;        // j-range start = js*320
  const int lrow = lane & 15, lhi = lane >> 4;
  const size_t base = (size_t)n * HWP * 64;
  const size_t cbase = (size_t)n * HWP;
  char* ws = smem + wid * 8704;      // this wave's private LDS slice

  // A-fragments straight from swizzled global (same XOR formula as LDS read)
  f16x8 Ah[2][4];
  #pragma unroll
  for (int kk = 0; kk < 2; ++kk)
    #pragma unroll
    for (int t = 0; t < 4; ++t) {
      const int row = i0 + t * 16 + lrow;
      Ah[kk][t] = *(const f16x8*)(qh + base + (size_t)row * 64 +
                                  (size_t)(((kk * 4 + lhi) ^ (row & 7)) * 8));
    }

  // q-centers in regs; C/D row = lhi*4 + r  -> vector f32x4 loads
  float qcx[4][4], qcy[4][4];
  #pragma unroll
  for (int tr = 0; tr < 4; ++tr) {
    f32x4 vx = *(const f32x4*)(cqxp + cbase + i0 + tr * 16 + lhi * 4);
    f32x4 vy = *(const f32x4*)(cqyp + cbase + i0 + tr * 16 + lhi * 4);
    #pragma unroll
    for (int r = 0; r < 4; ++r) { qcx[tr][r] = vx[r]; qcy[tr][r] = vy[r]; }
  }

  // Each STAGE = exactly 5 VMEM ops (4 tile gloads + 1 center gload)
  #define STAGE(c, b)                                                          \
  {                                                                            \
    const int j0 = js * 320 + (c) * 32;                                        \
    _Pragma("unroll")                                                          \
    for (int pass = 0; pass < 4; ++pass) {                                     \
      const int idx = pass * 64 + lane;                                        \
      gload16(kh + base + (size_t)(j0 + (idx >> 3)) * 64 + (idx & 7) * 8,      \
              ws + (b) * 4352 + idx * 16);                                     \
    }                                                                          \
    if (lane < 16) {                                                           \
      const float* csrc = (lane < 8) ? (ckxp + cbase + j0 + lane * 4)          \
                                     : (ckyp + cbase + j0 + (lane - 8) * 4);   \
      gload16(csrc, ws + (b) * 4352 + 4096 + lane * 16);                       \
    }                                                                          \
  }

  f32x2 num2 = (f32x2){0.f, 0.f};
  unsigned int dcnt = 0;

  STAGE(0, 0);   // prologue: chunk 0 into buf 0

  #define CHUNK_BODY(c, b, DO_STAGE)                                           \
  {                                                                            \
    if (DO_STAGE) {                                                            \
      STAGE((c) + 1, (b) ^ 1);                        /* prefetch next */      \
      asm volatile("s_waitcnt vmcnt(5)" ::: "memory"); /* chunk c landed */    \
    } else {                                                                   \
      asm volatile("s_waitcnt vmcnt(0)" ::: "memory");                         \
    }                                                                          \
    f16x8 Bh[2][2];                                                            \
    _Pragma("unroll")                                                          \
    for (int kk = 0; kk < 2; ++kk)                                             \
      _Pragma("unroll")                                                        \
      for (int t2 = 0; t2 < 2; ++t2) {                                         \
        const int jr = t2 * 16 + lrow;                                         \
        const int boff = jr * 128 + (((kk * 4 + lhi) ^ (jr & 7)) << 4);        \
        Bh[kk][t2] = *(const f16x8*)(ws + (b) * 4352 + boff);                  \
      }                                                                        \
    const float* skc = (const float*)(ws + (b) * 4352 + 4096);                 \
    f32x2 kx2, ky2;                                                            \
    kx2.x = skc[lrow];       kx2.y = skc[16 + lrow];                           \
    ky2.x = skc[32 + lrow];  ky2.y = skc[48 + lrow];                           \
    f32x4 acc[4][2];                                                           \
    _Pragma("unroll")                                                          \
    for (int a = 0; a < 4; ++a)                                                \
      _Pragma("unroll")                                                        \
      for (int c2 = 0; c2 < 2; ++c2) acc[a][c2] = (f32x4){0.f, 0.f, 0.f, 0.f};\
    __builtin_amdgcn_s_setprio(1);                                             \
    _Pragma("unroll")                                                          \
    for (int kk = 0; kk < 2; ++kk)                                             \
      _Pragma("unroll")                                                        \
      for (int tr = 0; tr < 4; ++tr)                                           \
        _Pragma("unroll")                                                      \
        for (int tc = 0; tc < 2; ++tc)                                         \
          acc[tr][tc] = __builtin_amdgcn_mfma_f32_16x16x32_f16(                \
              Ah[kk][tr], Bh[kk][tc], acc[tr][tc], 0, 0, 0);                   \
    __builtin_amdgcn_s_setprio(0);                                             \
    _Pragma("unroll")                                                          \
    for (int tr = 0; tr < 4; ++tr) {                                           \
      _Pragma("unroll")                                                        \
      for (int r = 0; r < 4; ++r) {                                            \
        const float qx = qcx[tr][r], qy = qcy[tr][r];                          \
        f32x2 dx, dy;                                                          \
        dx.x = qx - kx2.x; dx.y = qx - kx2.y;                                  \
        dy.x = qy - ky2.x; dy.y = qy - ky2.y;                                  \
        f32x2 d2 = dx * dx;                                                    \
        d2.x = fmaf(dy.x, dy.x, d2.x);                                         \
        d2.y = fmaf(dy.y, dy.y, d2.y);                                         \
        const bool m0 = d2.x < 0.48999998f;  /* 0.7^2 */                       \
        const bool m1 = d2.y < 0.48999998f;                                    \
        f32x2 sel;                                                             \
        sel.x = m0 ? acc[tr][0][r] : 0.f;                                      \
        sel.y = m1 ? acc[tr][1][r] : 0.f;                                      \
        num2 += sel;                                                           \
        dcnt += (unsigned int)__popcll(__ballot(m0));  /* scalar pipe */       \
        dcnt += (unsigned int)__popcll(__ballot(m1));                          \
      }                                                                        \
    }                                                                          \
  }

  for (int it = 0; it < 5; ++it) {
    const int c0 = it * 2;
    CHUNK_BODY(c0, 0, true);                 // chunk 2it   (buf0), stage 2it+1
    CHUNK_BODY(c0 + 1, 1, (c0 + 2 < 10));    // chunk 2it+1 (buf1), stage 2it+2
  }
  #undef CHUNK_BODY
  #undef STAGE

  // wave-level reduce, then 4-way merge (first and only barrier)
  float num = num2.x + num2.y;
  #pragma unroll
  for (int off = 32; off > 0; off >>= 1) num += __shfl_down(num, off);
  if (lane == 0) {
    redns[wid * 2] = num;
    redns[wid * 2 + 1] = (float)dcnt;
  }
  __syncthreads();
  if (tid == 0) {
    float tn = 0.f, td = 0.f;
    #pragma unroll
    for (int w = 0; w < 4; ++w) { tn += redns[w * 2]; td += redns[w * 2 + 1]; }
    partial[bid * 2] = tn;
    partial[bid * 2 + 1] = td;
  }
}

// ---------------- Kernel 3: final reduce over 125 partials per batch.
// partial[] indexed by bid: batch n owns bids {n, n+8, ...}.
__global__ __launch_bounds__(256) void finalize_kernel(const float* __restrict__ partial,
                                                       float* __restrict__ out) {
  __shared__ float rat[8];
  const int tid = threadIdx.x;
  const int n = tid >> 5, s = tid & 31;
  float num = 0.f, den = 0.f;
  for (int p = s; p < 125; p += 32) {
    num += partial[(p * 8 + n) * 2];
    den += partial[(p * 8 + n) * 2 + 1];
  }
  #pragma unroll
  for (int off = 16; off > 0; off >>= 1) {
    num += __shfl_down(num, off, 32);
    den += __shfl_down(den, off, 32);
  }
  if (s == 0) rat[n] = num / (den + 1e-6f);
  __syncthreads();
  if (tid == 0) {
    float t = 0.f;
    #pragma unroll
    for (int i = 0; i < 8; ++i) t += rat[i];
    out[0] = -0.25f * t;  // -2 * mean over 8 batches
  }
}

extern "C" void kernel_launch(void* const* d_in, const int* in_sizes, int n_in,
                              void* d_out, int out_size, void* d_ws, size_t ws_size,
                              hipStream_t stream) {
  const float* q   = (const float*)d_in[0];
  const float* k   = (const float*)d_in[1];
  const float* cqx = (const float*)d_in[2];
  const float* cqy = (const float*)d_in[3];
  const float* ckx = (const float*)d_in[4];
  const float* cky = (const float*)d_in[5];

  const size_t ARR = (size_t)NB * HWP * 64;
  ushort_t* qh = (ushort_t*)d_ws;
  ushort_t* kh = qh + ARR;
  float* cqxp = (float*)(kh + ARR);
  float* cqyp = cqxp + (size_t)NB * HWP;
  float* ckxp = cqyp + (size_t)NB * HWP;
  float* ckyp = ckxp + (size_t)NB * HWP;
  float* partial = ckyp + (size_t)NB * HWP;

  norm_cast_kernel<<<dim3(400, 2), 256, 0, stream>>>(
      q, k, cqx, cqy, ckx, cky, qh, kh, cqxp, cqyp, ckxp, ckyp);
  pair_sum_kernel<<<1000, 256, 0, stream>>>(
      qh, kh, cqxp, cqyp, ckxp, ckyp, partial);
  finalize_kernel<<<1, 256, 0, stream>>>(partial, (float*)d_out);
}